// Round 6
// baseline (75.149 us; speedup 1.0000x reference)
//
#include <hip/hip_runtime.h>

// FullAttention_Spatial: N=4, L=S=1024, H=16, E=D=64, NUM_POS=2, fp32 in/out.
//
// score = temp*(QK + attn_mask[l,s] + klm[n,s]) + pos_table[pos[n,l,s]][h]
// pos in {0,1} => bias = T0[h] + bit*(T1[h]-T0[h]); T0 cancels in softmax.
// Log2-domain softmax; Q pre-scaled by temp2 = temp*log2e.
//
// R5: occupancy doubling. 2-wave blocks (128 thr), 64 q/block, grid 1024
// -> 4 blocks/CU (160KB LDS exactly), 16 waves/CU, 4 waves/SIMD.
// Same cross-tile pipeline as R4: body(i) = {stage(i+1); QK^T(i) || PV(i-1)
// one 16-MFMA block; bias+softmax(i); pack P(i) in-register (plswap)}.
// K dbuf x2, V dbuf x3. One barrier/body. 32x32x16 MFMA, 32 q/wave.
//
// Layouts (m74/m101): C of 32x32: col=lane&31, row=(reg&3)+8*(reg>>2)+4*(lane>>5).
// A-frag: row=lane&31, k=8*(lane>>5)+j. B-frag: col=lane&31, k=8*(lane>>5)+j.

typedef __attribute__((ext_vector_type(8))) __bf16 bf16x8;
typedef __attribute__((ext_vector_type(16))) float f32x16;
typedef __attribute__((ext_vector_type(4))) unsigned int u32x4;

#define TEMP2 (0.125f * 1.4426950408889634f)
#define LG2E 1.4426950408889634f

static __device__ __forceinline__ unsigned short f2bf(float x) {
  unsigned int u = __builtin_bit_cast(unsigned int, x);
  u += 0x7FFFu + ((u >> 16) & 1u);
  return (unsigned short)(u >> 16);
}
static __device__ __forceinline__ unsigned int cvtpk(float lo, float hi) {
  unsigned int r;
  asm("v_cvt_pk_bf16_f32 %0, %1, %2" : "=v"(r) : "v"(lo), "v"(hi));
  return r;
}
static __device__ __forceinline__ void gload16(const void* g, void* l) {
  __builtin_amdgcn_global_load_lds((const __attribute__((address_space(1))) void*)g,
                                   (__attribute__((address_space(3))) void*)l, 16, 0, 0);
}
// After: a = {a.lo32, b.lo32}, b = {a.hi32, b.hi32}
static __device__ __forceinline__ void plswap(unsigned int& a, unsigned int& b) {
  asm("v_permlane32_swap_b32 %0, %1" : "+v"(a), "+v"(b));
}

// ---------------- fused prepass (unchanged) ----------------
__global__ __launch_bounds__(256) void k_prep(
    const int* __restrict__ pos, unsigned int* __restrict__ pospk,
    const float* __restrict__ K, unsigned short* __restrict__ Kp,
    const float* __restrict__ V, unsigned short* __restrict__ Vt,
    const float* __restrict__ mask, const float* __restrict__ klm,
    unsigned short* __restrict__ CM, int use_cm) {
  __shared__ float ld[64][65];
  int b = blockIdx.x;
  int tid = threadIdx.x;
  if (b < 256) {
    int idx = b * 256 + tid;
    int s = (idx >> 4) & 1023;
    const float* src = K + idx * 64;
    unsigned short row[64];
#pragma unroll
    for (int j = 0; j < 16; ++j) {
      float4 v = *(const float4*)(src + j * 4);
      row[j*4+0] = f2bf(v.x); row[j*4+1] = f2bf(v.y);
      row[j*4+2] = f2bf(v.z); row[j*4+3] = f2bf(v.w);
    }
    int n = idx >> 14, h = idx & 15;
    unsigned short* dst = Kp + ((n * 16 + h) * 1024 + s) * 64;
#pragma unroll
    for (int bb = 0; bb < 8; ++bb) {
      int pb = bb ^ (s & 7);
      *(u32x4*)(dst + pb * 8) = *(const u32x4*)(&row[bb * 8]);
    }
  } else if (b < 1280) {
    int vb = b - 256;
    int t = vb & 15, h = (vb >> 4) & 15, n = vb >> 8;
    {
      int s = tid >> 2, dq = (tid & 3) * 16;
      const float* src = V + ((n * 1024 + t * 64 + s) * 16 + h) * 64 + dq;
#pragma unroll
      for (int j = 0; j < 4; ++j) {
        float4 v = *(const float4*)(src + j * 4);
        ld[s][dq + j*4 + 0] = v.x; ld[s][dq + j*4 + 1] = v.y;
        ld[s][dq + j*4 + 2] = v.z; ld[s][dq + j*4 + 3] = v.w;
      }
    }
    __syncthreads();
    {
      int d = tid >> 2, sq = (tid & 3) * 16;
      unsigned short vals[16];
#pragma unroll
      for (int k = 0; k < 16; ++k) vals[k] = f2bf(ld[sq + k][d]);
      unsigned short* dst = Vt + ((n * 16 + h) * 64 + d) * 1024 + t * 64;
#pragma unroll
      for (int cb = 0; cb < 2; ++cb) {
        int blk = (sq >> 3) + cb;
        int pb = blk ^ (d & 7);
        *(u32x4*)(dst + pb * 8) = *(const u32x4*)(&vals[cb * 8]);
      }
    }
  } else if (b < 2304) {
    if (!use_cm) return;
    int flat = (b - 1280) * 256 * 16 + tid * 16;
    int n = flat >> 20, l = (flat >> 10) & 1023, s0 = flat & 1023;
    const float* mrow = mask + l * 1024 + s0;
    const float* krow = klm + n * 1024 + s0;
    unsigned int o[8];
#pragma unroll
    for (int j = 0; j < 4; ++j) {
      float4 mv = *(const float4*)(mrow + j * 4);
      float4 kv = *(const float4*)(krow + j * 4);
      o[j*2+0] = cvtpk((mv.x + kv.x) * TEMP2, (mv.y + kv.y) * TEMP2);
      o[j*2+1] = cvtpk((mv.z + kv.z) * TEMP2, (mv.w + kv.w) * TEMP2);
    }
    *(u32x4*)(CM + flat)     = *(const u32x4*)(&o[0]);
    *(u32x4*)(CM + flat + 8) = *(const u32x4*)(&o[4]);
  } else {
    int gi = (b - 2304) * 256 + tid;
    int v = pos[gi];
    unsigned long long m = __ballot(v & 1);
    int lane = tid & 63;
    if (lane == 0) pospk[gi >> 5] = (unsigned int)m;
    else if (lane == 32) pospk[gi >> 5] = (unsigned int)(m >> 32);
  }
}

// ---------------- main flash-attention kernel ----------------
// grid 1024 = (lblk<<6) | (h<<2) | n ; 2 waves x 32 q-rows = 64 q/block.
template <bool USE_CM>
__global__ __launch_bounds__(128, 4) void k_attn(
    const float* __restrict__ Q, const float* __restrict__ mask,
    const float* __restrict__ klm, const float* __restrict__ ptab,
    const unsigned int* __restrict__ pospk,
    const unsigned short* __restrict__ Kp, const unsigned short* __restrict__ Vt,
    const unsigned short* __restrict__ CMp,
    float* __restrict__ out) {
  __shared__ __align__(16) unsigned short Kt[2][4096];   // [64 s][64 e] swizzled
  __shared__ __align__(16) unsigned short Vts[3][4096];  // [64 d][64 s] swizzled

  int bid = blockIdx.x;
  int n = bid & 3, h = (bid >> 2) & 15, lblk = bid >> 6;
  int tid = threadIdx.x;
  int w = tid >> 6, lane = tid & 63;
  int l31 = lane & 31, h5 = lane >> 5;
  int l = lblk * 64 + w * 32 + l31;    // this lane's q-row (global)

  // Q fragments (B of swapped QK^T), pre-scaled by temp2
  const float* qrow = Q + ((n * 1024 + l) * 16 + h) * 64;
  bf16x8 qf[4];
#pragma unroll
  for (int ke = 0; ke < 4; ++ke) {
    float4 a = *(const float4*)(qrow + ke * 16 + h5 * 8);
    float4 b = *(const float4*)(qrow + ke * 16 + h5 * 8 + 4);
    u32x4 pk;
    pk[0] = cvtpk(a.x * TEMP2, a.y * TEMP2);
    pk[1] = cvtpk(a.z * TEMP2, a.w * TEMP2);
    pk[2] = cvtpk(b.x * TEMP2, b.y * TEMP2);
    pk[3] = cvtpk(b.z * TEMP2, b.w * TEMP2);
    qf[ke] = __builtin_bit_cast(bf16x8, pk);
  }
  const float delta2 = (ptab[16 + h] - ptab[h]) * LG2E;

  float mrun = -1e30f, lrun = 0.f;
  f32x16 Oc0 = {0,0,0,0,0,0,0,0,0,0,0,0,0,0,0,0};
  f32x16 Oc1 = {0,0,0,0,0,0,0,0,0,0,0,0,0,0,0,0};
  u32x4 pfA = {0,0,0,0}, pfB = {0,0,0,0}, pfC = {0,0,0,0}, pfD = {0,0,0,0};

  const unsigned short* KpB = Kp + (n * 16 + h) * 65536;
  const unsigned short* VtB = Vt + (n * 16 + h) * 65536;
  const unsigned short* CMb = USE_CM ? (CMp + (n * 1024 + l) * 1024) : nullptr;
  const float* mrowB = mask + l * 1024;
  const float* krowB = klm + n * 1024;
  const unsigned int* posB = pospk + (n * 1024 + l) * 32;

  // loop-invariant LDS read offsets (shorts): col slot per K-step, row base
  const int x7 = l31 & 7;
  const int co0 = ((0 + h5) ^ x7) * 8;
  const int co1 = ((2 + h5) ^ x7) * 8;
  const int co2 = ((4 + h5) ^ x7) * 8;
  const int co3 = ((6 + h5) ^ x7) * 8;
  const int rb = l31 * 64;
  const int h4 = h5 * 4;

  // staging addresses (each wave stages 32 K-rows and 32 V-rows per tile)
  const unsigned short* kS = KpB + w * 2048 + lane * 8;
  const unsigned short* vS = VtB + (w * 32 + (lane >> 3)) * 1024 + (lane & 7) * 8;
  const int kD = w * 2048 + lane * 8;  // LDS dst (shorts), +j*512 per chunk

#define LDK(KB, OFF) __builtin_bit_cast(bf16x8, *(const u32x4*)&Kt[KB][OFF])
#define LDV(VB, OFF) __builtin_bit_cast(bf16x8, *(const u32x4*)&Vts[VB][OFF])

  // ---- prologue: stage tile 0 (K->kb0, V->vb0); prefetch pos/bias tile 0 ----
#pragma unroll
  for (int j = 0; j < 4; ++j) {
    gload16(kS + j * 512, &Kt[0][kD + j * 512]);
    gload16(vS + j * 8192, &Vts[0][kD + j * 512]);
  }
  uint2 pwv = *(const uint2*)(posB);
  uint2 cmq[8];
  if constexpr (USE_CM) {
#pragma unroll
    for (int q8 = 0; q8 < 8; ++q8)
      cmq[q8] = *(const uint2*)(CMb + (q8 >> 2) * 32 + (q8 & 3) * 8 + h4);
  }
  __syncthreads();

#define BODY(T, KB, KSTG, VRD, VST, DO_PV, STG)                                \
  {                                                                            \
    uint2 npwv = {0, 0};                                                       \
    uint2 ncmq[8];                                                             \
    if (STG) {                                                                 \
      const int Tn = (T) + 1;                                                  \
      _Pragma("unroll")                                                        \
      for (int j = 0; j < 4; ++j) {                                            \
        gload16(kS + Tn * 4096 + j * 512, &Kt[KSTG][kD + j * 512]);            \
        gload16(vS + Tn * 64 + j * 8192, &Vts[VST][kD + j * 512]);             \
      }                                                                        \
      npwv = *(const uint2*)(posB + Tn * 2);                                   \
      if constexpr (USE_CM) {                                                  \
        _Pragma("unroll")                                                      \
        for (int q8 = 0; q8 < 8; ++q8)                                         \
          ncmq[q8] = *(const uint2*)(CMb + Tn * 64 + (q8 >> 2) * 32 +          \
                                     (q8 & 3) * 8 + h4);                       \
      }                                                                        \
    }                                                                          \
    /* ---- MFMA block: QK^T(T) and PV(T-1), all independent ---- */           \
    f32x16 sv0 = {0,0,0,0,0,0,0,0,0,0,0,0,0,0,0,0};                            \
    f32x16 sv1 = {0,0,0,0,0,0,0,0,0,0,0,0,0,0,0,0};                            \
    __builtin_amdgcn_s_setprio(1);                                             \
    sv0 = __builtin_amdgcn_mfma_f32_32x32x16_bf16(LDK(KB, rb + co0), qf[0], sv0, 0, 0, 0); \
    sv1 = __builtin_amdgcn_mfma_f32_32x32x16_bf16(LDK(KB, rb + 2048 + co0), qf[0], sv1, 0, 0, 0); \
    if (DO_PV) {                                                               \
      bf16x8 p = __builtin_bit_cast(bf16x8, pfA);                              \
      Oc0 = __builtin_amdgcn_mfma_f32_32x32x16_bf16(LDV(VRD, rb + co0), p, Oc0, 0, 0, 0); \
      Oc1 = __builtin_amdgcn_mfma_f32_32x32x16_bf16(LDV(VRD, rb + 2048 + co0), p, Oc1, 0, 0, 0); \
    }                                                                          \
    sv0 = __builtin_amdgcn_mfma_f32_32x32x16_bf16(LDK(KB, rb + co1), qf[1], sv0, 0, 0, 0); \
    sv1 = __builtin_amdgcn_mfma_f32_32x32x16_bf16(LDK(KB, rb + 2048 + co1), qf[1], sv1, 0, 0, 0); \
    if (DO_PV) {                                                               \
      bf16x8 p = __builtin_bit_cast(bf16x8, pfB);                              \
      Oc0 = __builtin_amdgcn_mfma_f32_32x32x16_bf16(LDV(VRD, rb + co1), p, Oc0, 0, 0, 0); \
      Oc1 = __builtin_amdgcn_mfma_f32_32x32x16_bf16(LDV(VRD, rb + 2048 + co1), p, Oc1, 0, 0, 0); \
    }                                                                          \
    sv0 = __builtin_amdgcn_mfma_f32_32x32x16_bf16(LDK(KB, rb + co2), qf[2], sv0, 0, 0, 0); \
    sv1 = __builtin_amdgcn_mfma_f32_32x32x16_bf16(LDK(KB, rb + 2048 + co2), qf[2], sv1, 0, 0, 0); \
    if (DO_PV) {                                                               \
      bf16x8 p = __builtin_bit_cast(bf16x8, pfC);                              \
      Oc0 = __builtin_amdgcn_mfma_f32_32x32x16_bf16(LDV(VRD, rb + co2), p, Oc0, 0, 0, 0); \
      Oc1 = __builtin_amdgcn_mfma_f32_32x32x16_bf16(LDV(VRD, rb + 2048 + co2), p, Oc1, 0, 0, 0); \
    }                                                                          \
    sv0 = __builtin_amdgcn_mfma_f32_32x32x16_bf16(LDK(KB, rb + co3), qf[3], sv0, 0, 0, 0); \
    sv1 = __builtin_amdgcn_mfma_f32_32x32x16_bf16(LDK(KB, rb + 2048 + co3), qf[3], sv1, 0, 0, 0); \
    if (DO_PV) {                                                               \
      bf16x8 p = __builtin_bit_cast(bf16x8, pfD);                              \
      Oc0 = __builtin_amdgcn_mfma_f32_32x32x16_bf16(LDV(VRD, rb + co3), p, Oc0, 0, 0, 0); \
      Oc1 = __builtin_amdgcn_mfma_f32_32x32x16_bf16(LDV(VRD, rb + 2048 + co3), p, Oc1, 0, 0, 0); \
    }                                                                          \
    __builtin_amdgcn_s_setprio(0);                                             \
    /* ---- bias: CM + pos bit, s=(i)+8*r2+4*h5 (+32 for sv1) ---- */          \
    {                                                                          \
      unsigned pws0 = pwv.x >> h4;                                             \
      unsigned pws1 = pwv.y >> h4;                                             \
      _Pragma("unroll")                                                        \
      for (int r2 = 0; r2 < 4; ++r2) {                                         \
        float b0[4], b1[4];                                                    \
        if constexpr (USE_CM) {                                                \
          b0[0] = __builtin_bit_cast(float, cmq[r2].x << 16);                  \
          b0[1] = __builtin_bit_cast(float, cmq[r2].x & 0xFFFF0000u);          \
          b0[2] = __builtin_bit_cast(float, cmq[r2].y << 16);                  \
          b0[3] = __builtin_bit_cast(float, cmq[r2].y & 0xFFFF0000u);          \
          b1[0] = __builtin_bit_cast(float, cmq[4 + r2].x << 16);              \
          b1[1] = __builtin_bit_cast(float, cmq[4 + r2].x & 0xFFFF0000u);      \
          b1[2] = __builtin_bit_cast(float, cmq[4 + r2].y << 16);              \
          b1[3] = __builtin_bit_cast(float, cmq[4 + r2].y & 0xFFFF0000u);      \
        } else {                                                               \
          float4 mv0 = *(const float4*)(mrowB + (T) * 64 + r2 * 8 + h4);       \
          float4 kv0 = *(const float4*)(krowB + (T) * 64 + r2 * 8 + h4);       \
          float4 mv1 = *(const float4*)(mrowB + (T) * 64 + 32 + r2 * 8 + h4);  \
          float4 kv1 = *(const float4*)(krowB + (T) * 64 + 32 + r2 * 8 + h4);  \
          b0[0] = (mv0.x + kv0.x) * TEMP2; b0[1] = (mv0.y + kv0.y) * TEMP2;    \
          b0[2] = (mv0.z + kv0.z) * TEMP2; b0[3] = (mv0.w + kv0.w) * TEMP2;    \
          b1[0] = (mv1.x + kv1.x) * TEMP2; b1[1] = (mv1.y + kv1.y) * TEMP2;    \
          b1[2] = (mv1.z + kv1.z) * TEMP2; b1[3] = (mv1.w + kv1.w) * TEMP2;    \
        }                                                                      \
        _Pragma("unroll")                                                      \
        for (int i = 0; i < 4; ++i) {                                          \
          float bit0 = (float)((pws0 >> (r2 * 8 + i)) & 1u);                   \
          float bit1 = (float)((pws1 >> (r2 * 8 + i)) & 1u);                   \
          sv0[r2 * 4 + i] = fmaf(bit0, delta2, sv0[r2 * 4 + i] + b0[i]);       \
          sv1[r2 * 4 + i] = fmaf(bit1, delta2, sv1[r2 * 4 + i] + b1[i]);       \
        }                                                                      \
      }                                                                        \
    }                                                                          \
    /* ---- online softmax (row q: lanes l31, l31+32) ---- */                  \
    {                                                                          \
      float m8[8];                                                             \
      _Pragma("unroll")                                                        \
      for (int i = 0; i < 8; ++i)                                              \
        m8[i] = fmaxf(fmaxf(sv0[2 * i], sv0[2 * i + 1]),                       \
                      fmaxf(sv1[2 * i], sv1[2 * i + 1]));                      \
      float m4a = fmaxf(m8[0], m8[1]), m4b = fmaxf(m8[2], m8[3]);              \
      float m4c = fmaxf(m8[4], m8[5]), m4d = fmaxf(m8[6], m8[7]);              \
      float tmax = fmaxf(fmaxf(m4a, m4b), fmaxf(m4c, m4d));                    \
      tmax = fmaxf(tmax, __shfl_xor(tmax, 32));                                \
      if (!__all(tmax <= mrun + 4.0f)) {                                       \
        float mnew = fmaxf(mrun, tmax);                                        \
        float sc = __builtin_amdgcn_exp2f(mrun - mnew);                        \
        lrun *= sc;                                                            \
        Oc0 *= sc; Oc1 *= sc;                                                  \
        mrun = mnew;                                                           \
      }                                                                        \
      float s8[8];                                                             \
      _Pragma("unroll")                                                        \
      for (int i = 0; i < 8; ++i) {                                            \
        float p0 = __builtin_amdgcn_exp2f(sv0[2 * i] - mrun);                  \
        float p1 = __builtin_amdgcn_exp2f(sv0[2 * i + 1] - mrun);              \
        float p2 = __builtin_amdgcn_exp2f(sv1[2 * i] - mrun);                  \
        float p3 = __builtin_amdgcn_exp2f(sv1[2 * i + 1] - mrun);              \
        sv0[2 * i] = p0; sv0[2 * i + 1] = p1;                                  \
        sv1[2 * i] = p2; sv1[2 * i + 1] = p3;                                  \
        s8[i] = (p0 + p1) + (p2 + p3);                                         \
      }                                                                        \
      float s4a = s8[0] + s8[1], s4b = s8[2] + s8[3];                          \
      float s4c = s8[4] + s8[5], s4d = s8[6] + s8[7];                          \
      lrun += (s4a + s4b) + (s4c + s4d);   /* lane-partial; combined at end */ \
    }                                                                          \
    /* ---- pack P(T) -> pfA..pfD (pre-swapped B-frags) ---- */                \
    {                                                                          \
      unsigned a0 = cvtpk(sv0[0], sv0[1]),   a1 = cvtpk(sv0[2], sv0[3]);       \
      unsigned a2 = cvtpk(sv0[4], sv0[5]),   a3 = cvtpk(sv0[6], sv0[7]);       \
      plswap(a0, a2); plswap(a1, a3);                                          \
      pfA[0] = a0; pfA[1] = a1; pfA[2] = a2; pfA[3] = a3;                      \
      unsigned b0_ = cvtpk(sv0[8], sv0[9]),   b1_ = cvtpk(sv0[10], sv0[11]);   \
      unsigned b2_ = cvtpk(sv0[12], sv0[13]), b3_ = cvtpk(sv0[14], sv0[15]);   \
      plswap(b0_, b2_); plswap(b1_, b3_);                                      \
      pfB[0] = b0_; pfB[1] = b1_; pfB[2] = b2_; pfB[3] = b3_;                  \
      unsigned c0 = cvtpk(sv1[0], sv1[1]),   c1 = cvtpk(sv1[2], sv1[3]);       \
      unsigned c2 = cvtpk(sv1[4], sv1[5]),   c3 = cvtpk(sv1[6], sv1[7]);       \
      plswap(c0, c2); plswap(c1, c3);                                          \
      pfC[0] = c0; pfC[1] = c1; pfC[2] = c2; pfC[3] = c3;                      \
      unsigned d0 = cvtpk(sv1[8], sv1[9]),   d1 = cvtpk(sv1[10], sv1[11]);     \
      unsigned d2 = cvtpk(sv1[12], sv1[13]), d3 = cvtpk(sv1[14], sv1[15]);     \
      plswap(d0, d2); plswap(d1, d3);                                          \
      pfD[0] = d0; pfD[1] = d1; pfD[2] = d2; pfD[3] = d3;                      \
    }                                                                          \
    if (STG) {                                                                 \
      __syncthreads();                                                         \
      pwv = npwv;                                                              \
      if constexpr (USE_CM) {                                                  \
        _Pragma("unroll")                                                      \
        for (int q8 = 0; q8 < 8; ++q8) cmq[q8] = ncmq[q8];                     \
      }                                                                        \
    }                                                                          \
  }

  //      T  KB KSTG VRD VST PV STG
  BODY( 0, 0, 1,  0,  1, 0, 1)
  BODY( 1, 1, 0,  0,  2, 1, 1)
  BODY( 2, 0, 1,  1,  0, 1, 1)
  BODY( 3, 1, 0,  2,  1, 1, 1)
  BODY( 4, 0, 1,  0,  2, 1, 1)
  BODY( 5, 1, 0,  1,  0, 1, 1)
  BODY( 6, 0, 1,  2,  1, 1, 1)
  BODY( 7, 1, 0,  0,  2, 1, 1)
  BODY( 8, 0, 1,  1,  0, 1, 1)
  BODY( 9, 1, 0,  2,  1, 1, 1)
  BODY(10, 0, 1,  0,  2, 1, 1)
  BODY(11, 1, 0,  1,  0, 1, 1)
  BODY(12, 0, 1,  2,  1, 1, 1)
  BODY(13, 1, 0,  0,  2, 1, 1)
  BODY(14, 0, 1,  1,  0, 1, 1)
  BODY(15, 1, 0,  2,  0, 1, 0)
#undef BODY

  // ---- epilogue PV(15): V[15] lives in vbuf[15%3=0] ----
  __builtin_amdgcn_s_setprio(1);
  {
    bf16x8 p = __builtin_bit_cast(bf16x8, pfA);
    Oc0 = __builtin_amdgcn_mfma_f32_32x32x16_bf16(LDV(0, rb + co0), p, Oc0, 0, 0, 0);
    Oc1 = __builtin_amdgcn_mfma_f32_32x32x16_bf16(LDV(0, rb + 2048 + co0), p, Oc1, 0, 0, 0);
    p = __builtin_bit_cast(bf16x8, pfB);
    Oc0 = __builtin_amdgcn_mfma_f32_32x32x16_bf16(LDV(0, rb + co1), p, Oc0, 0, 0, 0);
    Oc1 = __builtin_amdgcn_mfma_f32_32x32x16_bf16(LDV(0, rb + 2048 + co1), p, Oc1, 0, 0, 0);
    p = __builtin_bit_cast(bf16x8, pfC);
    Oc0 = __builtin_amdgcn_mfma_f32_32x32x16_bf16(LDV(0, rb + co2), p, Oc0, 0, 0, 0);
    Oc1 = __builtin_amdgcn_mfma_f32_32x32x16_bf16(LDV(0, rb + 2048 + co2), p, Oc1, 0, 0, 0);
    p = __builtin_bit_cast(bf16x8, pfD);
    Oc0 = __builtin_amdgcn_mfma_f32_32x32x16_bf16(LDV(0, rb + co3), p, Oc0, 0, 0, 0);
    Oc1 = __builtin_amdgcn_mfma_f32_32x32x16_bf16(LDV(0, rb + 2048 + co3), p, Oc1, 0, 0, 0);
  }
  __builtin_amdgcn_s_setprio(0);
#undef LDK
#undef LDV

  // ---- epilogue: combine lane-partial lrun, /l, store O^T ----
  lrun += __shfl_xor(lrun, 32);
  float inv = 1.0f / lrun;
  float* orow = out + ((n * 1024 + l) * 16 + h) * 64;
#pragma unroll
  for (int r2 = 0; r2 < 4; ++r2) {
    float4 o;
    o.x = Oc0[4 * r2 + 0] * inv; o.y = Oc0[4 * r2 + 1] * inv;
    o.z = Oc0[4 * r2 + 2] * inv; o.w = Oc0[4 * r2 + 3] * inv;
    *(float4*)(orow + r2 * 8 + h4) = o;
    o.x = Oc1[4 * r2 + 0] * inv; o.y = Oc1[4 * r2 + 1] * inv;
    o.z = Oc1[4 * r2 + 2] * inv; o.w = Oc1[4 * r2 + 3] * inv;
    *(float4*)(orow + 32 + r2 * 8 + h4) = o;
  }
}

extern "C" void kernel_launch(void* const* d_in, const int* in_sizes, int n_in,
                              void* d_out, int out_size, void* d_ws, size_t ws_size,
                              hipStream_t stream) {
  const float* Q    = (const float*)d_in[0];
  const float* K    = (const float*)d_in[1];
  const float* V    = (const float*)d_in[2];
  const float* mask = (const float*)d_in[3];
  const float* klm  = (const float*)d_in[4];
  const float* ptab = (const float*)d_in[5];
  const int*   pos  = (const int*)d_in[6];
  float* out = (float*)d_out;

  char* ws = (char*)d_ws;
  unsigned int*   pospk = (unsigned int*)ws;                               // 512 KB
  unsigned short* Kp    = (unsigned short*)(ws + (1 << 19));               // 8 MB
  unsigned short* Vt    = (unsigned short*)(ws + (1 << 19) + (8 << 20));   // 8 MB
  unsigned short* CM    = (unsigned short*)(ws + (1 << 19) + (16 << 20));  // 8 MB
  const size_t need_cm = (size_t)(1 << 19) + (size_t)(24 << 20);
  const bool use_cm = ws_size >= need_cm;

  k_prep<<<18688, 256, 0, stream>>>(pos, pospk, K, Kp, V, Vt, mask, klm, CM,
                                    use_cm ? 1 : 0);
  if (use_cm) {
    k_attn<true><<<1024, 128, 0, stream>>>(Q, mask, klm, ptab, pospk, Kp, Vt, CM, out);
  } else {
    k_attn<false><<<1024, 128, 0, stream>>>(Q, mask, klm, ptab, pospk, Kp, Vt, nullptr, out);
  }
}